// Round 1
// baseline (698.413 us; speedup 1.0000x reference)
//
#include <hip/hip_runtime.h>
#include <hip/hip_bf16.h>
#include <cstddef>

#define TB 256

constexpr int Bb = 8, Ss = 4096, Dd = 1024, Kk = 64, Hh = 8, HDd = 128;
constexpr float INV_TEMP = 10.0f;
constexpr float ATTN_SCALE = 0.08838834764831845f; // 1/sqrt(128)

// workspace layout (floats)
constexpr size_t N_RW  = (size_t)Bb * Ss * Kk;      // 2,097,152
constexpr size_t N_AKD = (size_t)Bb * Kk * Dd;      // 524,288
constexpr size_t N_PS  = (size_t)Bb * Hh * Kk * Kk; // 262,144
constexpr size_t OFF_RW  = 0;
constexpr size_t OFF_AI  = OFF_RW  + N_RW;
constexpr size_t OFF_QKV = OFF_AI  + N_AKD;
constexpr size_t OFF_ATT = OFF_QKV + 3 * N_AKD;
constexpr size_t OFF_AO  = OFF_ATT + N_AKD;
constexpr size_t OFF_AOP = OFF_AO  + N_AKD;
constexpr size_t OFF_PS  = OFF_AOP + N_AKD;
// total = 6,029,312 floats = 24.1 MB

__global__ __launch_bounds__(TB) void k_zero(float* __restrict__ p, int n4) {
    int i = blockIdx.x * TB + threadIdx.x;
    if (i < n4) ((float4*)p)[i] = make_float4(0.f, 0.f, 0.f, 0.f);
}

// ---------------------------------------------------------------------------
// Routing: per 64-token tile, compute rw = softmax((2*(ef*w_e+b_e) +
//          relu(x@w1+b1)@w2+b2) / TEMP) over K=64.
// grid = B * (S/64) = 512 blocks
// ---------------------------------------------------------------------------
__global__ __launch_bounds__(TB) void k_routing(
    const float* __restrict__ x, const float* __restrict__ efas,
    const float* __restrict__ w_e, const float* __restrict__ b_e,
    const float* __restrict__ w1, const float* __restrict__ b1,
    const float* __restrict__ w2, const float* __restrict__ b2,
    float* __restrict__ rw)
{
    __shared__ float xs[64][68];   // x tile [64 tok][64 d] (reused as h)
    __shared__ float ws[64][68];   // w1 chunk / w2
    const int tid  = threadIdx.x;
    const int b    = blockIdx.x >> 6;
    const int t0   = (blockIdx.x & 63) << 6;
    const int kcol = tid & 63;
    const int wv   = tid >> 6;           // wave id 0..3; rows wv*16..wv*16+15

    float acc[16];
#pragma unroll
    for (int i = 0; i < 16; ++i) acc[i] = 0.f;

    const size_t xbase = ((size_t)b * Ss + t0) * Dd;
    for (int dc = 0; dc < 16; ++dc) {
#pragma unroll
        for (int p = 0; p < 4; ++p) {
            int q = tid + p * TB;
            int r = q >> 4, c = (q & 15) << 2;
            float4 v = *(const float4*)&x[xbase + (size_t)r * Dd + dc * 64 + c];
            *(float4*)&xs[r][c] = v;
        }
#pragma unroll
        for (int p = 0; p < 4; ++p) {
            int q = tid + p * TB;
            int r = q >> 4, c = (q & 15) << 2;
            float4 v = *(const float4*)&w1[(size_t)(dc * 64 + r) * Kk + c];
            *(float4*)&ws[r][c] = v;
        }
        __syncthreads();
#pragma unroll 4
        for (int d = 0; d < 64; ++d) {
            float wval = ws[d][kcol];
#pragma unroll
            for (int i = 0; i < 16; ++i)
                acc[i] += xs[wv * 16 + i][d] * wval;
        }
        __syncthreads();
    }

    // h = relu(acc + b1) -> xs
    float b1k = b1[kcol];
#pragma unroll
    for (int i = 0; i < 16; ++i)
        xs[wv * 16 + i][kcol] = fmaxf(acc[i] + b1k, 0.f);
#pragma unroll
    for (int p = 0; p < 4; ++p) {
        int q = tid + p * TB;
        int r = q >> 4, c = (q & 15) << 2;
        float4 v = *(const float4*)&w2[(size_t)r * Kk + c];
        *(float4*)&ws[r][c] = v;
    }
    __syncthreads();

    const float w_ek = w_e[kcol], b_ek = b_e[kcol], b2k = b2[kcol];
#pragma unroll 2
    for (int i = 0; i < 16; ++i) {
        int r = wv * 16 + i;
        float cacc = b2k;
#pragma unroll 8
        for (int j = 0; j < 64; ++j)
            cacc += xs[r][j] * ws[j][kcol];
        float ef = efas[(size_t)b * Ss + t0 + r];
        float t  = (2.f * (ef * w_ek + b_ek) + cacc) * INV_TEMP;
        float m  = t;
#pragma unroll
        for (int off = 32; off; off >>= 1) m = fmaxf(m, __shfl_xor(m, off));
        float e = __expf(t - m);
        float s = e;
#pragma unroll
        for (int off = 32; off; off >>= 1) s += __shfl_xor(s, off);
        rw[((size_t)b * Ss + t0 + r) * Kk + kcol] = e / s;
    }
}

// ---------------------------------------------------------------------------
// Anchor aggregation: ai[b,k,d] = sum_s rw[b,s,k] * x[b,s,d]
// grid = B * 8 dtiles * 16 schunks = 1024; fp32 atomics into zeroed ai
// ---------------------------------------------------------------------------
__global__ __launch_bounds__(TB) void k_anchor(
    const float* __restrict__ x, const float* __restrict__ rw,
    float* __restrict__ ai)
{
    __shared__ float rws[64][68];
    __shared__ float xs[64][132];
    const int tid  = threadIdx.x;
    const int sc   = blockIdx.x & 15;
    const int dt   = (blockIdx.x >> 4) & 7;
    const int b    = blockIdx.x >> 7;
    const int dcol = tid & 63;
    const int wv   = tid >> 6;

    float acc0[16], acc1[16];
#pragma unroll
    for (int i = 0; i < 16; ++i) { acc0[i] = 0.f; acc1[i] = 0.f; }

    for (int ssub = 0; ssub < 4; ++ssub) {
        int sbase = sc * 256 + ssub * 64;
#pragma unroll
        for (int p = 0; p < 4; ++p) {
            int q = tid + p * TB;
            int r = q >> 4, c = (q & 15) << 2;
            float4 v = *(const float4*)&rw[((size_t)b * Ss + sbase + r) * Kk + c];
            *(float4*)&rws[r][c] = v;
        }
#pragma unroll
        for (int p = 0; p < 8; ++p) {
            int q = tid + p * TB;
            int r = q >> 5, c = (q & 31) << 2;
            float4 v = *(const float4*)&x[((size_t)b * Ss + sbase + r) * Dd + dt * 128 + c];
            *(float4*)&xs[r][c] = v;
        }
        __syncthreads();
#pragma unroll 2
        for (int s = 0; s < 64; ++s) {
            float x0 = xs[s][dcol], x1 = xs[s][dcol + 64];
#pragma unroll
            for (int i = 0; i < 16; ++i) {
                float w = rws[s][wv * 16 + i];
                acc0[i] += w * x0;
                acc1[i] += w * x1;
            }
        }
        __syncthreads();
    }
#pragma unroll
    for (int i = 0; i < 16; ++i) {
        size_t base = ((size_t)b * Kk + wv * 16 + i) * Dd + dt * 128;
        atomicAdd(&ai[base + dcol], acc0[i]);
        atomicAdd(&ai[base + dcol + 64], acc1[i]);
    }
}

// ---------------------------------------------------------------------------
// Anchor-space GEMM: C[b,m,n] = A[b,m,:1024] @ W[:,n] (+ bias)
// grid = B * (NTOT/128)
// ---------------------------------------------------------------------------
template <int NTOT, bool HASBIAS>
__global__ __launch_bounds__(TB) void k_gemm_anchor(
    const float* __restrict__ A, const float* __restrict__ W,
    const float* __restrict__ bias, float* __restrict__ C)
{
    __shared__ float as[64][68];
    __shared__ float ws[64][132];
    const int tid  = threadIdx.x;
    constexpr int NT = NTOT / 128;
    const int nt   = blockIdx.x % NT;
    const int b    = blockIdx.x / NT;
    const int ncol = tid & 63;
    const int wv   = tid >> 6;

    float acc0[16], acc1[16];
#pragma unroll
    for (int i = 0; i < 16; ++i) { acc0[i] = 0.f; acc1[i] = 0.f; }

    for (int dc = 0; dc < 16; ++dc) {
#pragma unroll
        for (int p = 0; p < 4; ++p) {
            int q = tid + p * TB;
            int r = q >> 4, c = (q & 15) << 2;
            float4 v = *(const float4*)&A[((size_t)b * Kk + r) * Dd + dc * 64 + c];
            *(float4*)&as[r][c] = v;
        }
#pragma unroll
        for (int p = 0; p < 8; ++p) {
            int q = tid + p * TB;
            int r = q >> 5, c = (q & 31) << 2;
            float4 v = *(const float4*)&W[(size_t)(dc * 64 + r) * NTOT + nt * 128 + c];
            *(float4*)&ws[r][c] = v;
        }
        __syncthreads();
#pragma unroll 2
        for (int d = 0; d < 64; ++d) {
            float w0 = ws[d][ncol], w1v = ws[d][ncol + 64];
#pragma unroll
            for (int i = 0; i < 16; ++i) {
                float a = as[wv * 16 + i][d];
                acc0[i] += a * w0;
                acc1[i] += a * w1v;
            }
        }
        __syncthreads();
    }
    float bb0 = HASBIAS ? bias[nt * 128 + ncol] : 0.f;
    float bb1 = HASBIAS ? bias[nt * 128 + ncol + 64] : 0.f;
#pragma unroll
    for (int i = 0; i < 16; ++i) {
        size_t o = ((size_t)b * Kk + wv * 16 + i) * NTOT + nt * 128;
        C[o + ncol]      = acc0[i] + bb0;
        C[o + ncol + 64] = acc1[i] + bb1;
    }
}

// ---------------------------------------------------------------------------
// Attention scores + softmax: ps[b,h,a,a2] = softmax_a2(q.k / sqrt(HD))
// grid = B*H = 64
// ---------------------------------------------------------------------------
__global__ __launch_bounds__(TB) void k_attn_scores(
    const float* __restrict__ qkv, float* __restrict__ psg)
{
    __shared__ float qs[64][69];
    __shared__ float ks[64][69];
    const int tid  = threadIdx.x;
    const int b    = blockIdx.x >> 3, h = blockIdx.x & 7;
    const int lane = tid & 63, wv = tid >> 6;

    float sc[16];
#pragma unroll
    for (int i = 0; i < 16; ++i) sc[i] = 0.f;

    for (int dch = 0; dch < 2; ++dch) {
#pragma unroll
        for (int p = 0; p < 4; ++p) {
            int q = tid + p * TB;
            int r = q >> 4, c = (q & 15) << 2;
            size_t base = ((size_t)b * Kk + r) * 3 * Dd + h * HDd + dch * 64 + c;
            float4 vq = *(const float4*)&qkv[base];
            float4 vk = *(const float4*)&qkv[base + Dd];
            qs[r][c] = vq.x; qs[r][c + 1] = vq.y; qs[r][c + 2] = vq.z; qs[r][c + 3] = vq.w;
            ks[r][c] = vk.x; ks[r][c + 1] = vk.y; ks[r][c + 2] = vk.z; ks[r][c + 3] = vk.w;
        }
        __syncthreads();
#pragma unroll 2
        for (int i = 0; i < 16; ++i) {
            int a = wv * 16 + i;
            float s = 0.f;
#pragma unroll 8
            for (int d = 0; d < 64; ++d)
                s += qs[a][d] * ks[lane][d];
            sc[i] += s;
        }
        __syncthreads();
    }
#pragma unroll
    for (int i = 0; i < 16; ++i) {
        float t = sc[i] * ATTN_SCALE;
        float m = t;
#pragma unroll
        for (int off = 32; off; off >>= 1) m = fmaxf(m, __shfl_xor(m, off));
        float e = __expf(t - m);
        float s = e;
#pragma unroll
        for (int off = 32; off; off >>= 1) s += __shfl_xor(s, off);
        psg[(((size_t)b * Hh + h) * Kk + wv * 16 + i) * Kk + lane] = e / s;
    }
}

// ---------------------------------------------------------------------------
// Attention PV: att[b,a,h*128+hd] = sum_a2 ps[b,h,a,a2] * v[b,a2,h,hd]
// grid = B*H = 64
// ---------------------------------------------------------------------------
__global__ __launch_bounds__(TB) void k_attn_pv(
    const float* __restrict__ qkv, const float* __restrict__ psg,
    float* __restrict__ att)
{
    __shared__ float vs[64][132];
    __shared__ float ps[64][68];
    const int tid  = threadIdx.x;
    const int b    = blockIdx.x >> 3, h = blockIdx.x & 7;
    const int lane = tid & 63, wv = tid >> 6;

#pragma unroll
    for (int p = 0; p < 8; ++p) {
        int q = tid + p * TB;
        int r = q >> 5, c = (q & 31) << 2;
        float4 v = *(const float4*)&qkv[((size_t)b * Kk + r) * 3 * Dd + 2 * Dd + h * HDd + c];
        *(float4*)&vs[r][c] = v;
    }
#pragma unroll
    for (int p = 0; p < 4; ++p) {
        int q = tid + p * TB;
        int r = q >> 4, c = (q & 15) << 2;
        float4 v = *(const float4*)&psg[(((size_t)b * Hh + h) * Kk + r) * Kk + c];
        *(float4*)&ps[r][c] = v;
    }
    __syncthreads();

    float o0[16], o1[16];
#pragma unroll
    for (int i = 0; i < 16; ++i) { o0[i] = 0.f; o1[i] = 0.f; }
#pragma unroll 2
    for (int a2 = 0; a2 < 64; ++a2) {
        float v0 = vs[a2][lane], v1 = vs[a2][lane + 64];
#pragma unroll
        for (int i = 0; i < 16; ++i) {
            float p = ps[wv * 16 + i][a2];
            o0[i] += p * v0;
            o1[i] += p * v1;
        }
    }
#pragma unroll
    for (int i = 0; i < 16; ++i) {
        size_t o = ((size_t)b * Kk + wv * 16 + i) * Dd + h * HDd;
        att[o + lane]      = o0[i];
        att[o + lane + 64] = o1[i];
    }
}

// ---------------------------------------------------------------------------
// Scatter-back + folded output projection:
// out[b,s,:] = sum_k rw[b,s,k] * aop[b,k,:] + b_p
// grid = B * (S/64) = 512
// ---------------------------------------------------------------------------
__global__ __launch_bounds__(TB) void k_scatter(
    const float* __restrict__ rw, const float* __restrict__ aop,
    const float* __restrict__ b_p, float* __restrict__ out)
{
    __shared__ float rws[64][68];
    __shared__ float as[64][132];
    const int tid  = threadIdx.x;
    const int b    = blockIdx.x >> 6;
    const int t0   = (blockIdx.x & 63) << 6;
    const int dcol = tid & 63;
    const int wv   = tid >> 6;

#pragma unroll
    for (int p = 0; p < 4; ++p) {
        int q = tid + p * TB;
        int r = q >> 4, c = (q & 15) << 2;
        float4 v = *(const float4*)&rw[((size_t)b * Ss + t0 + r) * Kk + c];
        *(float4*)&rws[r][c] = v;
    }
    for (int dch = 0; dch < 8; ++dch) {
#pragma unroll
        for (int p = 0; p < 8; ++p) {
            int q = tid + p * TB;
            int r = q >> 5, c = (q & 31) << 2;
            float4 v = *(const float4*)&aop[((size_t)b * Kk + r) * Dd + dch * 128 + c];
            *(float4*)&as[r][c] = v;
        }
        __syncthreads();
        float o0[16], o1[16];
#pragma unroll
        for (int i = 0; i < 16; ++i) { o0[i] = 0.f; o1[i] = 0.f; }
#pragma unroll 2
        for (int kk = 0; kk < 64; ++kk) {
            float v0 = as[kk][dcol], v1 = as[kk][dcol + 64];
#pragma unroll
            for (int i = 0; i < 16; ++i) {
                float w = rws[wv * 16 + i][kk];
                o0[i] += w * v0;
                o1[i] += w * v1;
            }
        }
        float bp0 = b_p[dch * 128 + dcol], bp1 = b_p[dch * 128 + dcol + 64];
#pragma unroll
        for (int i = 0; i < 16; ++i) {
            size_t o = ((size_t)b * Ss + t0 + wv * 16 + i) * Dd + dch * 128;
            out[o + dcol]      = o0[i] + bp0;
            out[o + dcol + 64] = o1[i] + bp1;
        }
        __syncthreads();
    }
}

extern "C" void kernel_launch(void* const* d_in, const int* in_sizes, int n_in,
                              void* d_out, int out_size, void* d_ws, size_t ws_size,
                              hipStream_t stream)
{
    const float* x     = (const float*)d_in[0];
    const float* efas  = (const float*)d_in[1];
    const float* w_e   = (const float*)d_in[2];
    const float* b_e   = (const float*)d_in[3];
    const float* w1    = (const float*)d_in[4];
    const float* b1    = (const float*)d_in[5];
    const float* w2    = (const float*)d_in[6];
    const float* b2    = (const float*)d_in[7];
    const float* w_qkv = (const float*)d_in[8];
    const float* b_qkv = (const float*)d_in[9];
    const float* w_o   = (const float*)d_in[10];
    const float* b_o   = (const float*)d_in[11];
    const float* w_p   = (const float*)d_in[12];
    const float* b_p   = (const float*)d_in[13];
    float* out = (float*)d_out;
    float* ws  = (float*)d_ws;

    float* rw  = ws + OFF_RW;
    float* ai  = ws + OFF_AI;
    float* qkv = ws + OFF_QKV;
    float* att = ws + OFF_ATT;
    float* ao  = ws + OFF_AO;
    float* aop = ws + OFF_AOP;
    float* psg = ws + OFF_PS;

    hipLaunchKernelGGL(k_zero, dim3(512), dim3(TB), 0, stream, ai, (int)(N_AKD / 4));
    hipLaunchKernelGGL(k_routing, dim3(512), dim3(TB), 0, stream,
                       x, efas, w_e, b_e, w1, b1, w2, b2, rw);
    hipLaunchKernelGGL(k_anchor, dim3(1024), dim3(TB), 0, stream, x, rw, ai);
    hipLaunchKernelGGL((k_gemm_anchor<3072, true>), dim3(Bb * 24), dim3(TB), 0, stream,
                       ai, w_qkv, b_qkv, qkv);
    hipLaunchKernelGGL(k_attn_scores, dim3(Bb * Hh), dim3(TB), 0, stream, qkv, psg);
    hipLaunchKernelGGL(k_attn_pv, dim3(Bb * Hh), dim3(TB), 0, stream, qkv, psg, att);
    hipLaunchKernelGGL((k_gemm_anchor<1024, true>), dim3(Bb * 8), dim3(TB), 0, stream,
                       att, w_o, b_o, ao);
    hipLaunchKernelGGL((k_gemm_anchor<1024, false>), dim3(Bb * 8), dim3(TB), 0, stream,
                       ao, w_p, nullptr, aop);
    hipLaunchKernelGGL(k_scatter, dim3(512), dim3(TB), 0, stream, rw, aop, b_p, out);
}

// Round 2
// 262.910 us; speedup vs baseline: 2.6565x; 2.6565x over previous
//
#include <hip/hip_runtime.h>
#include <cstddef>

#define TB 256

constexpr int Bb = 8, Ss = 4096, Dd = 1024, Kk = 64, Hh = 8;
constexpr float INV_TEMP = 10.0f;
constexpr float ATTN_SCALE = 0.08838834764831845f; // 1/sqrt(128)

// workspace layout (floats)
constexpr size_t N_RW  = (size_t)Bb * Ss * Kk;   // 2,097,152
constexpr size_t N_AKD = (size_t)Bb * Kk * Dd;   // 524,288
constexpr size_t OFF_RW  = 0;
constexpr size_t OFF_AI  = OFF_RW  + N_RW;
constexpr size_t OFF_QKV = OFF_AI  + N_AKD;
constexpr size_t OFF_ATT = OFF_QKV + 3 * N_AKD;
constexpr size_t OFF_AO  = OFF_ATT + N_AKD;
constexpr size_t OFF_AOP = OFF_AO  + N_AKD;
// total = 5,767,424 floats = 23.1 MB

typedef __attribute__((ext_vector_type(8))) short bf16x8;
typedef __attribute__((ext_vector_type(4))) float f32x4;

#define MFMA(a, b, c) __builtin_amdgcn_mfma_f32_16x16x32_bf16(a, b, c, 0, 0, 0)

__device__ inline ushort f2bf(float f) {
    union { float f; uint u; } v; v.f = f;
    return (ushort)((v.u + 0x7fffu + ((v.u >> 16) & 1u)) >> 16);
}
__device__ inline float bf2f(ushort h) {
    union { uint u; float f; } v; v.u = ((uint)h) << 16;
    return v.f;
}
__device__ inline void split2(float f, ushort& h, ushort& l) {
    h = f2bf(f);
    l = f2bf(f - bf2f(h));
}

// ---- swizzled LDS bf16 tile, logical [row][64] (stride 72 ushorts = 144B) ---
// byte(row,s) = row*144 + (((s>>3) ^ ((row>>2)&7)) << 4) + (s&7)*2
__device__ inline void st4(ushort* t, int row, int s0, ushort4 v) {
    char* p = (char*)t + row * 144 + ((((s0 >> 3) ^ ((row >> 2) & 7)) << 4) | ((s0 & 7) << 1));
    *(ushort4*)p = v;
}
__device__ inline void st1(ushort* t, int row, int s, ushort v) {
    char* p = (char*)t + row * 144 + ((((s >> 3) ^ ((row >> 2) & 7)) << 4) | ((s & 7) << 1));
    *(ushort*)p = v;
}
__device__ inline bf16x8 ldfrag(const ushort* t, int row, int sblk) {
    const char* p = (const char*)t + row * 144 + (((sblk ^ ((row >> 2) & 7))) << 4);
    return *(const bf16x8*)p;
}
// natural fill: split one float4 at (row, s0..s0+3)
__device__ inline void natf(ushort* thi, ushort* tlo, int row, int s0, float4 v) {
    ushort h0,h1,h2,h3,l0,l1,l2,l3;
    split2(v.x,h0,l0); split2(v.y,h1,l1); split2(v.z,h2,l2); split2(v.w,h3,l3);
    st4(thi, row, s0, make_ushort4(h0,h1,h2,h3));
    st4(tlo, row, s0, make_ushort4(l0,l1,l2,l3));
}
// transposed fill: a..d are source rows s0..s0+3, cols rowbase..rowbase+3
__device__ inline void trf(ushort* thi, ushort* tlo, int rowbase, int s0,
                           float4 a, float4 b, float4 c, float4 d) {
    float m[4][4] = {{a.x,b.x,c.x,d.x},{a.y,b.y,c.y,d.y},
                     {a.z,b.z,c.z,d.z},{a.w,b.w,c.w,d.w}};
#pragma unroll
    for (int i = 0; i < 4; ++i) {
        ushort h[4], l[4];
#pragma unroll
        for (int j = 0; j < 4; ++j) split2(m[i][j], h[j], l[j]);
        st4(thi, rowbase + i, s0, make_ushort4(h[0],h[1],h[2],h[3]));
        st4(tlo, rowbase + i, s0, make_ushort4(l[0],l[1],l[2],l[3]));
    }
}
// 3-term split-bf16 accumulate (emulated fp32)
__device__ inline f32x4 mm3(bf16x8 ah, bf16x8 al, bf16x8 bh, bf16x8 bl, f32x4 c) {
    c = MFMA(ah, bh, c);
    c = MFMA(ah, bl, c);
    c = MFMA(al, bh, c);
    return c;
}

__global__ __launch_bounds__(TB) void k_zero(float* __restrict__ p, int n4) {
    int i = blockIdx.x * TB + threadIdx.x;
    if (i < n4) ((float4*)p)[i] = make_float4(0.f, 0.f, 0.f, 0.f);
}

// ---------------------------------------------------------------------------
// Routing: rw = softmax((2*(ef*w_e+b_e) + relu(x@w1+b1)@w2 + b2)/TEMP)
// grid = 8b * 32 stiles (128 tokens each) = 256 blocks
// ---------------------------------------------------------------------------
__global__ __launch_bounds__(TB) void k_routing(
    const float* __restrict__ x, const float* __restrict__ efas,
    const float* __restrict__ w_e, const float* __restrict__ b_e,
    const float* __restrict__ w1, const float* __restrict__ b1,
    const float* __restrict__ w2, const float* __restrict__ b2,
    float* __restrict__ rw)
{
    __shared__ __align__(16) ushort xa_hi[128*72], xa_lo[128*72]; // x chunk / h
    __shared__ __align__(16) ushort wa_hi[64*72],  wa_lo[64*72];  // w1T chunk / w2T
    const int tid = threadIdx.x, lane = tid & 63, wv = tid >> 6;
    const int b = blockIdx.x & 7, t0 = (blockIdx.x >> 3) * 128;
    const int r15 = lane & 15, g = lane >> 4;

    f32x4 acc[2][4];
#pragma unroll
    for (int mt = 0; mt < 2; ++mt)
#pragma unroll
      for (int nt = 0; nt < 4; ++nt) acc[mt][nt] = (f32x4)0.f;

    for (int kc = 0; kc < 16; ++kc) {
        const int k0 = kc * 64;
#pragma unroll
        for (int p = 0; p < 8; ++p) {           // x natural fill [128 tok][64 d]
            int q = tid + p * TB;
            int row = q >> 4, s0 = (q & 15) << 2;
            float4 v = *(const float4*)&x[((size_t)b*Ss + t0 + row)*Dd + k0 + s0];
            natf(xa_hi, xa_lo, row, s0, v);
        }
        {                                        // w1 transposed fill [64n][64k]
            int n0 = (tid & 15) << 2, s0 = (tid >> 4) << 2;
            const float* base = &w1[(size_t)(k0 + s0) * Kk + n0];
            float4 a  = *(const float4*)(base);
            float4 bq = *(const float4*)(base + Kk);
            float4 cq = *(const float4*)(base + 2*Kk);
            float4 dq = *(const float4*)(base + 3*Kk);
            trf(wa_hi, wa_lo, n0, s0, a, bq, cq, dq);
        }
        __syncthreads();
#pragma unroll
        for (int ks = 0; ks < 2; ++ks) {
            bf16x8 ah[2], al[2];
#pragma unroll
            for (int mt = 0; mt < 2; ++mt) {
                int row = wv*32 + mt*16 + r15;
                ah[mt] = ldfrag(xa_hi, row, ks*4 + g);
                al[mt] = ldfrag(xa_lo, row, ks*4 + g);
            }
#pragma unroll
            for (int nt = 0; nt < 4; ++nt) {
                bf16x8 bh = ldfrag(wa_hi, nt*16 + r15, ks*4 + g);
                bf16x8 bl = ldfrag(wa_lo, nt*16 + r15, ks*4 + g);
#pragma unroll
                for (int mt = 0; mt < 2; ++mt)
                    acc[mt][nt] = mm3(ah[mt], al[mt], bh, bl, acc[mt][nt]);
            }
        }
        __syncthreads();
    }
    // h = relu(acc + b1) -> xa tiles (each wave writes only its own rows)
    float b1v[4];
#pragma unroll
    for (int nt = 0; nt < 4; ++nt) b1v[nt] = b1[nt*16 + r15];
#pragma unroll
    for (int mt = 0; mt < 2; ++mt)
#pragma unroll
      for (int nt = 0; nt < 4; ++nt)
#pragma unroll
        for (int j = 0; j < 4; ++j) {
            float hv = fmaxf(acc[mt][nt][j] + b1v[nt], 0.f);
            ushort hh, hl; split2(hv, hh, hl);
            int row = wv*32 + mt*16 + g*4 + j, col = nt*16 + r15;
            st1(xa_hi, row, col, hh);
            st1(xa_lo, row, col, hl);
        }
    {                                            // w2 transposed fill [64n][64k]
        int n0 = (tid & 15) << 2, s0 = (tid >> 4) << 2;
        const float* base = &w2[(size_t)s0 * Kk + n0];
        float4 a  = *(const float4*)(base);
        float4 bq = *(const float4*)(base + Kk);
        float4 cq = *(const float4*)(base + 2*Kk);
        float4 dq = *(const float4*)(base + 3*Kk);
        trf(wa_hi, wa_lo, n0, s0, a, bq, cq, dq);
    }
    __syncthreads();

    f32x4 acc2[2][4];
#pragma unroll
    for (int mt = 0; mt < 2; ++mt)
#pragma unroll
      for (int nt = 0; nt < 4; ++nt) acc2[mt][nt] = (f32x4)0.f;
#pragma unroll
    for (int ks = 0; ks < 2; ++ks) {
        bf16x8 ah[2], al[2];
#pragma unroll
        for (int mt = 0; mt < 2; ++mt) {
            int row = wv*32 + mt*16 + r15;
            ah[mt] = ldfrag(xa_hi, row, ks*4 + g);
            al[mt] = ldfrag(xa_lo, row, ks*4 + g);
        }
#pragma unroll
        for (int nt = 0; nt < 4; ++nt) {
            bf16x8 bh = ldfrag(wa_hi, nt*16 + r15, ks*4 + g);
            bf16x8 bl = ldfrag(wa_lo, nt*16 + r15, ks*4 + g);
#pragma unroll
            for (int mt = 0; mt < 2; ++mt)
                acc2[mt][nt] = mm3(ah[mt], al[mt], bh, bl, acc2[mt][nt]);
        }
    }
    // logits + softmax over k (4 ntiles x 16 lanes), write rw fp32
    float wev[4], bev[4], b2v[4];
#pragma unroll
    for (int nt = 0; nt < 4; ++nt) {
        wev[nt] = w_e[nt*16 + r15]; bev[nt] = b_e[nt*16 + r15]; b2v[nt] = b2[nt*16 + r15];
    }
#pragma unroll
    for (int mt = 0; mt < 2; ++mt)
#pragma unroll
      for (int j = 0; j < 4; ++j) {
        int row = wv*32 + mt*16 + g*4 + j;
        float ef = efas[(size_t)b*Ss + t0 + row];
        float t[4];
#pragma unroll
        for (int nt = 0; nt < 4; ++nt)
            t[nt] = (acc2[mt][nt][j] + b2v[nt] + 2.f*(ef*wev[nt] + bev[nt])) * INV_TEMP;
        float m = fmaxf(fmaxf(t[0],t[1]), fmaxf(t[2],t[3]));
#pragma unroll
        for (int off = 1; off <= 8; off <<= 1) m = fmaxf(m, __shfl_xor(m, off));
        float s = 0.f;
#pragma unroll
        for (int nt = 0; nt < 4; ++nt) { t[nt] = __expf(t[nt] - m); s += t[nt]; }
#pragma unroll
        for (int off = 1; off <= 8; off <<= 1) s += __shfl_xor(s, off);
        float inv = 1.f / s;
#pragma unroll
        for (int nt = 0; nt < 4; ++nt)
            rw[((size_t)b*Ss + t0 + row)*Kk + nt*16 + r15] = t[nt] * inv;
      }
}

// ---------------------------------------------------------------------------
// Anchor agg: ai[b,k,d] += sum_s rw[s,k]*x[s,d]   (3-term split MFMA, atomics)
// grid = 8b * 8dt(128d) * 8sc(512s) = 512
// ---------------------------------------------------------------------------
__global__ __launch_bounds__(TB) void k_anchor(
    const float* __restrict__ x, const float* __restrict__ rw, float* __restrict__ ai)
{
    __shared__ __align__(16) ushort at_hi[64*72],  at_lo[64*72];   // rwT [k][s]
    __shared__ __align__(16) ushort bt_hi[128*72], bt_lo[128*72];  // xT  [d][s]
    const int tid = threadIdx.x, lane = tid & 63, wv = tid >> 6;
    const int b = blockIdx.x & 7, dt = (blockIdx.x >> 3) & 7, sc = blockIdx.x >> 6;
    const int r15 = lane & 15, g = lane >> 4;

    f32x4 acc[4][2];
#pragma unroll
    for (int mt = 0; mt < 4; ++mt)
#pragma unroll
      for (int nt = 0; nt < 2; ++nt) acc[mt][nt] = (f32x4)0.f;

    for (int cc = 0; cc < 8; ++cc) {
        const int sb = sc*512 + cc*64;
        {                                        // rwT transposed fill [64k][64s]
            int k0 = (tid & 15) << 2, s0 = (tid >> 4) << 2;
            const float* base = &rw[((size_t)b*Ss + sb + s0)*Kk + k0];
            float4 a  = *(const float4*)(base);
            float4 bq = *(const float4*)(base + Kk);
            float4 cq = *(const float4*)(base + 2*Kk);
            float4 dq = *(const float4*)(base + 3*Kk);
            trf(at_hi, at_lo, k0, s0, a, bq, cq, dq);
        }
#pragma unroll
        for (int p = 0; p < 2; ++p) {            // xT transposed fill [128d][64s]
            int q = tid + p * TB;
            int d0 = (q & 31) << 2, s0 = (q >> 5) << 2;
            const float* base = &x[((size_t)b*Ss + sb + s0)*Dd + dt*128 + d0];
            float4 a  = *(const float4*)(base);
            float4 bq = *(const float4*)(base + Dd);
            float4 cq = *(const float4*)(base + 2*Dd);
            float4 dq = *(const float4*)(base + 3*Dd);
            trf(bt_hi, bt_lo, d0, s0, a, bq, cq, dq);
        }
        __syncthreads();
#pragma unroll
        for (int ks = 0; ks < 2; ++ks) {
            bf16x8 ah[4], al[4];
#pragma unroll
            for (int mt = 0; mt < 4; ++mt) {
                ah[mt] = ldfrag(at_hi, mt*16 + r15, ks*4 + g);
                al[mt] = ldfrag(at_lo, mt*16 + r15, ks*4 + g);
            }
#pragma unroll
            for (int nt = 0; nt < 2; ++nt) {
                int rn = wv*32 + nt*16 + r15;
                bf16x8 bh = ldfrag(bt_hi, rn, ks*4 + g);
                bf16x8 bl = ldfrag(bt_lo, rn, ks*4 + g);
#pragma unroll
                for (int mt = 0; mt < 4; ++mt)
                    acc[mt][nt] = mm3(ah[mt], al[mt], bh, bl, acc[mt][nt]);
            }
        }
        __syncthreads();
    }
#pragma unroll
    for (int mt = 0; mt < 4; ++mt)
#pragma unroll
      for (int nt = 0; nt < 2; ++nt)
#pragma unroll
        for (int j = 0; j < 4; ++j) {
            int k = mt*16 + g*4 + j;
            int d = dt*128 + wv*32 + nt*16 + r15;
            atomicAdd(&ai[((size_t)b*Kk + k)*Dd + d], acc[mt][nt][j]);
        }
}

// ---------------------------------------------------------------------------
// Anchor-space GEMM: C[b,64,N] = A[b,64,K] @ W[K,N] (+bias), 3-term split
// grid = 8b * (N/128)
// ---------------------------------------------------------------------------
template <int KDIM, int NDIM, bool HASBIAS>
__global__ __launch_bounds__(TB) void k_gemm_a(
    const float* __restrict__ A, const float* __restrict__ W,
    const float* __restrict__ bias, float* __restrict__ C)
{
    __shared__ __align__(16) ushort at_hi[64*72],  at_lo[64*72];
    __shared__ __align__(16) ushort bt_hi[128*72], bt_lo[128*72]; // WT [n][k]
    const int tid = threadIdx.x, lane = tid & 63, wv = tid >> 6;
    const int b = blockIdx.x & 7, n0 = (blockIdx.x >> 3) * 128;
    const int r15 = lane & 15, g = lane >> 4;

    f32x4 acc[4][2];
#pragma unroll
    for (int mt = 0; mt < 4; ++mt)
#pragma unroll
      for (int nt = 0; nt < 2; ++nt) acc[mt][nt] = (f32x4)0.f;

    for (int kc = 0; kc < KDIM/64; ++kc) {
        const int k0 = kc * 64;
#pragma unroll
        for (int p = 0; p < 4; ++p) {            // A natural fill [64][64]
            int q = tid + p * TB;
            int row = q >> 4, s0 = (q & 15) << 2;
            float4 v = *(const float4*)&A[((size_t)b*64 + row)*KDIM + k0 + s0];
            natf(at_hi, at_lo, row, s0, v);
        }
#pragma unroll
        for (int p = 0; p < 2; ++p) {            // W transposed fill [128n][64k]
            int q = tid + p * TB;
            int nn0 = (q & 31) << 2, s0 = (q >> 5) << 2;
            const float* base = &W[(size_t)(k0 + s0)*NDIM + n0 + nn0];
            float4 a  = *(const float4*)(base);
            float4 bq = *(const float4*)(base + NDIM);
            float4 cq = *(const float4*)(base + 2*(size_t)NDIM);
            float4 dq = *(const float4*)(base + 3*(size_t)NDIM);
            trf(bt_hi, bt_lo, nn0, s0, a, bq, cq, dq);
        }
        __syncthreads();
#pragma unroll
        for (int ks = 0; ks < 2; ++ks) {
            bf16x8 ah[4], al[4];
#pragma unroll
            for (int mt = 0; mt < 4; ++mt) {
                ah[mt] = ldfrag(at_hi, mt*16 + r15, ks*4 + g);
                al[mt] = ldfrag(at_lo, mt*16 + r15, ks*4 + g);
            }
#pragma unroll
            for (int nt = 0; nt < 2; ++nt) {
                int rn = wv*32 + nt*16 + r15;
                bf16x8 bh = ldfrag(bt_hi, rn, ks*4 + g);
                bf16x8 bl = ldfrag(bt_lo, rn, ks*4 + g);
#pragma unroll
                for (int mt = 0; mt < 4; ++mt)
                    acc[mt][nt] = mm3(ah[mt], al[mt], bh, bl, acc[mt][nt]);
            }
        }
        __syncthreads();
    }
#pragma unroll
    for (int nt = 0; nt < 2; ++nt) {
        int n = n0 + wv*32 + nt*16 + r15;
        float bb = HASBIAS ? bias[n] : 0.f;
#pragma unroll
        for (int mt = 0; mt < 4; ++mt)
#pragma unroll
          for (int j = 0; j < 4; ++j)
            C[((size_t)b*64 + mt*16 + g*4 + j)*NDIM + n] = acc[mt][nt][j] + bb;
    }
}

// ---------------------------------------------------------------------------
// Fused attention per (b,h): scores (3-term), softmax, PV (3-term)
// grid = 64
// ---------------------------------------------------------------------------
__global__ __launch_bounds__(TB) void k_attn(
    const float* __restrict__ qkv, float* __restrict__ att)
{
    __shared__ __align__(16) ushort qt_hi[64*72],  qt_lo[64*72];  // Q tile / probs
    __shared__ __align__(16) ushort kt_hi[64*72],  kt_lo[64*72];  // K tile
    __shared__ __align__(16) ushort vt_hi[128*72], vt_lo[128*72]; // VT [d][a]
    const int tid = threadIdx.x, lane = tid & 63, wv = tid >> 6;
    const int b = blockIdx.x >> 3, h = blockIdx.x & 7;
    const int r15 = lane & 15, g = lane >> 4;

    f32x4 accs[4];
#pragma unroll
    for (int nt = 0; nt < 4; ++nt) accs[nt] = (f32x4)0.f;

    for (int ch = 0; ch < 2; ++ch) {
        const int c0 = h*128 + ch*64;
#pragma unroll
        for (int p = 0; p < 4; ++p) {
            int q = tid + p * TB;
            int row = q >> 4, s0 = (q & 15) << 2;
            size_t base = ((size_t)b*64 + row)*3072 + c0 + s0;
            natf(qt_hi, qt_lo, row, s0, *(const float4*)&qkv[base]);
            natf(kt_hi, kt_lo, row, s0, *(const float4*)&qkv[base + 1024]);
        }
        __syncthreads();
#pragma unroll
        for (int ks = 0; ks < 2; ++ks) {
            bf16x8 ah = ldfrag(qt_hi, wv*16 + r15, ks*4 + g);
            bf16x8 al = ldfrag(qt_lo, wv*16 + r15, ks*4 + g);
#pragma unroll
            for (int nt = 0; nt < 4; ++nt) {
                bf16x8 bh = ldfrag(kt_hi, nt*16 + r15, ks*4 + g);
                bf16x8 bl = ldfrag(kt_lo, nt*16 + r15, ks*4 + g);
                accs[nt] = mm3(ah, al, bh, bl, accs[nt]);
            }
        }
        __syncthreads();
    }
    // softmax over anchors (4 ntiles x 16 lanes)
    float pr[4][4];
#pragma unroll
    for (int j = 0; j < 4; ++j) {
        float t[4];
#pragma unroll
        for (int nt = 0; nt < 4; ++nt) t[nt] = accs[nt][j] * ATTN_SCALE;
        float m = fmaxf(fmaxf(t[0],t[1]), fmaxf(t[2],t[3]));
#pragma unroll
        for (int off = 1; off <= 8; off <<= 1) m = fmaxf(m, __shfl_xor(m, off));
        float s = 0.f;
#pragma unroll
        for (int nt = 0; nt < 4; ++nt) { t[nt] = __expf(t[nt] - m); s += t[nt]; }
#pragma unroll
        for (int off = 1; off <= 8; off <<= 1) s += __shfl_xor(s, off);
        float inv = 1.f / s;
#pragma unroll
        for (int nt = 0; nt < 4; ++nt) pr[j][nt] = t[nt] * inv;
    }
    // probs -> qt tiles (own rows only)
#pragma unroll
    for (int j = 0; j < 4; ++j)
#pragma unroll
      for (int nt = 0; nt < 4; ++nt) {
        ushort hh, hl; split2(pr[j][nt], hh, hl);
        st1(qt_hi, wv*16 + g*4 + j, nt*16 + r15, hh);
        st1(qt_lo, wv*16 + g*4 + j, nt*16 + r15, hl);
      }
    // VT transposed fill [128d][64a]
#pragma unroll
    for (int p = 0; p < 2; ++p) {
        int q = tid + p * TB;
        int d0 = (q & 31) << 2, a0 = (q >> 5) << 2;
        const float* base = &qkv[((size_t)b*64 + a0)*3072 + 2048 + h*128 + d0];
        float4 a  = *(const float4*)(base);
        float4 bq = *(const float4*)(base + 3072);
        float4 cq = *(const float4*)(base + 2*3072);
        float4 dq = *(const float4*)(base + 3*3072);
        trf(vt_hi, vt_lo, d0, a0, a, bq, cq, dq);
    }
    __syncthreads();
    // PV
    f32x4 acc2[8];
#pragma unroll
    for (int nt = 0; nt < 8; ++nt) acc2[nt] = (f32x4)0.f;
#pragma unroll
    for (int ks = 0; ks < 2; ++ks) {
        bf16x8 ah = ldfrag(qt_hi, wv*16 + r15, ks*4 + g);
        bf16x8 al = ldfrag(qt_lo, wv*16 + r15, ks*4 + g);
#pragma unroll
        for (int nt = 0; nt < 8; ++nt) {
            bf16x8 bh = ldfrag(vt_hi, nt*16 + r15, ks*4 + g);
            bf16x8 bl = ldfrag(vt_lo, nt*16 + r15, ks*4 + g);
            acc2[nt] = mm3(ah, al, bh, bl, acc2[nt]);
        }
    }
#pragma unroll
    for (int nt = 0; nt < 8; ++nt)
#pragma unroll
      for (int j = 0; j < 4; ++j)
        att[((size_t)b*64 + wv*16 + g*4 + j)*1024 + h*128 + nt*16 + r15] = acc2[nt][j];
}

// ---------------------------------------------------------------------------
// Scatter-back: out[b,s,:] = rw[b,s,:] @ aop[b,:,:] + b_p   (3-term split)
// grid = 8b * 32 stiles(128 tok) * 8 dtiles(128 d) = 2048
// ---------------------------------------------------------------------------
__global__ __launch_bounds__(TB) void k_scatter(
    const float* __restrict__ rw, const float* __restrict__ aop,
    const float* __restrict__ b_p, float* __restrict__ out)
{
    __shared__ __align__(16) ushort at_hi[128*72], at_lo[128*72]; // rw [tok][k]
    __shared__ __align__(16) ushort bt_hi[128*72], bt_lo[128*72]; // aopT [d][k]
    const int tid = threadIdx.x, lane = tid & 63, wv = tid >> 6;
    const int b = blockIdx.x & 7, st = (blockIdx.x >> 3) & 31, dt = blockIdx.x >> 8;
    const int r15 = lane & 15, g = lane >> 4;
    const int t0 = st * 128;

#pragma unroll
    for (int p = 0; p < 8; ++p) {                // rw natural fill [128 tok][64 k]
        int q = tid + p * TB;
        int row = q >> 4, s0 = (q & 15) << 2;
        float4 v = *(const float4*)&rw[((size_t)b*Ss + t0 + row)*Kk + s0];
        natf(at_hi, at_lo, row, s0, v);
    }
#pragma unroll
    for (int p = 0; p < 2; ++p) {                // aopT transposed fill [128d][64k]
        int q = tid + p * TB;
        int d0 = (q & 31) << 2, k0q = (q >> 5) << 2;
        const float* base = &aop[((size_t)b*Kk + k0q)*Dd + dt*128 + d0];
        float4 a  = *(const float4*)(base);
        float4 bq = *(const float4*)(base + Dd);
        float4 cq = *(const float4*)(base + 2*Dd);
        float4 dq = *(const float4*)(base + 3*Dd);
        trf(bt_hi, bt_lo, d0, k0q, a, bq, cq, dq);
    }
    __syncthreads();

    f32x4 acc[2][8];
#pragma unroll
    for (int mt = 0; mt < 2; ++mt)
#pragma unroll
      for (int nt = 0; nt < 8; ++nt) acc[mt][nt] = (f32x4)0.f;
#pragma unroll
    for (int ks = 0; ks < 2; ++ks) {
        bf16x8 ah[2], al[2];
#pragma unroll
        for (int mt = 0; mt < 2; ++mt) {
            ah[mt] = ldfrag(at_hi, wv*32 + mt*16 + r15, ks*4 + g);
            al[mt] = ldfrag(at_lo, wv*32 + mt*16 + r15, ks*4 + g);
        }
#pragma unroll
        for (int nt = 0; nt < 8; ++nt) {
            bf16x8 bh = ldfrag(bt_hi, nt*16 + r15, ks*4 + g);
            bf16x8 bl = ldfrag(bt_lo, nt*16 + r15, ks*4 + g);
#pragma unroll
            for (int mt = 0; mt < 2; ++mt)
                acc[mt][nt] = mm3(ah[mt], al[mt], bh, bl, acc[mt][nt]);
        }
    }
#pragma unroll
    for (int nt = 0; nt < 8; ++nt) {
        float bb = b_p[dt*128 + nt*16 + r15];
#pragma unroll
        for (int mt = 0; mt < 2; ++mt)
#pragma unroll
          for (int j = 0; j < 4; ++j)
            out[((size_t)b*Ss + t0 + wv*32 + mt*16 + g*4 + j)*Dd + dt*128 + nt*16 + r15]
                = acc[mt][nt][j] + bb;
    }
}

extern "C" void kernel_launch(void* const* d_in, const int* in_sizes, int n_in,
                              void* d_out, int out_size, void* d_ws, size_t ws_size,
                              hipStream_t stream)
{
    const float* x     = (const float*)d_in[0];
    const float* efas  = (const float*)d_in[1];
    const float* w_e   = (const float*)d_in[2];
    const float* b_e   = (const float*)d_in[3];
    const float* w1    = (const float*)d_in[4];
    const float* b1    = (const float*)d_in[5];
    const float* w2    = (const float*)d_in[6];
    const float* b2    = (const float*)d_in[7];
    const float* w_qkv = (const float*)d_in[8];
    const float* b_qkv = (const float*)d_in[9];
    const float* w_o   = (const float*)d_in[10];
    const float* b_o   = (const float*)d_in[11];
    const float* w_p   = (const float*)d_in[12];
    const float* b_p   = (const float*)d_in[13];
    float* out = (float*)d_out;
    float* ws  = (float*)d_ws;

    float* rw  = ws + OFF_RW;
    float* ai  = ws + OFF_AI;
    float* qkv = ws + OFF_QKV;
    float* att = ws + OFF_ATT;
    float* ao  = ws + OFF_AO;
    float* aop = ws + OFF_AOP;

    hipLaunchKernelGGL(k_zero, dim3(512), dim3(TB), 0, stream, ai, (int)(N_AKD/4));
    hipLaunchKernelGGL(k_routing, dim3(256), dim3(TB), 0, stream,
                       x, efas, w_e, b_e, w1, b1, w2, b2, rw);
    hipLaunchKernelGGL(k_anchor, dim3(512), dim3(TB), 0, stream, x, rw, ai);
    hipLaunchKernelGGL((k_gemm_a<1024, 3072, true>), dim3(192), dim3(TB), 0, stream,
                       ai, w_qkv, b_qkv, qkv);
    hipLaunchKernelGGL(k_attn, dim3(64), dim3(TB), 0, stream, qkv, att);
    hipLaunchKernelGGL((k_gemm_a<1024, 1024, true>), dim3(64), dim3(TB), 0, stream,
                       att, w_o, b_o, ao);
    hipLaunchKernelGGL((k_gemm_a<1024, 1024, false>), dim3(64), dim3(TB), 0, stream,
                       ao, w_p, nullptr, aop);
    hipLaunchKernelGGL(k_scatter, dim3(2048), dim3(TB), 0, stream, rw, aop, b_p, out);
}